// Round 2
// baseline (265.095 us; speedup 1.0000x reference)
//
#include <hip/hip_runtime.h>

#define N_IMG 4
#define E_DIM 16
#define P_PIX 320000
#define G_PIX (P_PIX / 4)   // float4 groups per image
#define C_CLS 20
#define CK 19               // C - 1 (IGNORE = 0 excluded)
#define LDS_STRIDE 17       // 17 invertible mod 32 -> 20 labels hit 20 distinct banks
#define NREP 4              // replicated LDS accumulators to cut atomic serialization

// ws layout (floats):
#define SUMS_OFF 0
#define CNT_OFF  (N_IMG * C_CLS * E_DIM)            // 1280
#define MEAN_OFF (CNT_OFF + N_IMG * C_CLS)          // 1360
#define LOSS_OFF (MEAN_OFF + N_IMG * C_CLS * E_DIM) // 2640
#define WS_FLOATS (LOSS_OFF + 1)

// ---------------- Kernel 1: per-class sums + counts ----------------
__global__ void k_sums(const float* __restrict__ emb, const int* __restrict__ target,
                       float* __restrict__ ws) {
    __shared__ float lsum[NREP][C_CLS * LDS_STRIDE];
    __shared__ float lcnt[NREP][C_CLS];
    const int tid = threadIdx.x;
    const int n = blockIdx.y;
    const int rep = tid & (NREP - 1);

    for (int i = tid; i < NREP * C_CLS * LDS_STRIDE; i += blockDim.x)
        (&lsum[0][0])[i] = 0.f;
    for (int i = tid; i < NREP * C_CLS; i += blockDim.x)
        (&lcnt[0][0])[i] = 0.f;
    __syncthreads();

    const float4* emb4 = (const float4*)(emb + (size_t)n * E_DIM * P_PIX);
    const int4*   tgt4 = (const int4*)(target + (size_t)n * P_PIX);
    const int stride = gridDim.x * blockDim.x;

    for (int g = blockIdx.x * blockDim.x + tid; g < G_PIX; g += stride) {
        const int4 lab = tgt4[g];
        atomicAdd(&lcnt[rep][lab.x], 1.0f);
        atomicAdd(&lcnt[rep][lab.y], 1.0f);
        atomicAdd(&lcnt[rep][lab.z], 1.0f);
        atomicAdd(&lcnt[rep][lab.w], 1.0f);
        const int bx = lab.x * LDS_STRIDE, by = lab.y * LDS_STRIDE;
        const int bz = lab.z * LDS_STRIDE, bw = lab.w * LDS_STRIDE;
#pragma unroll
        for (int e = 0; e < E_DIM; e++) {
            const float4 v = emb4[(size_t)e * G_PIX + g];
            atomicAdd(&lsum[rep][bx + e], v.x);
            atomicAdd(&lsum[rep][by + e], v.y);
            atomicAdd(&lsum[rep][bz + e], v.z);
            atomicAdd(&lsum[rep][bw + e], v.w);
        }
    }
    __syncthreads();

    float* gsum = ws + SUMS_OFF + n * C_CLS * E_DIM;
    float* gcnt = ws + CNT_OFF + n * C_CLS;
    for (int i = tid; i < C_CLS * E_DIM; i += blockDim.x) {
        const int c = i / E_DIM, e = i % E_DIM;
        float v = 0.f;
#pragma unroll
        for (int r = 0; r < NREP; r++) v += lsum[r][c * LDS_STRIDE + e];
        atomicAdd(&gsum[i], v);
    }
    if (tid < C_CLS) {
        float v = 0.f;
#pragma unroll
        for (int r = 0; r < NREP; r++) v += lcnt[r][tid];
        atomicAdd(&gcnt[tid], v);
    }
}

// -------- Kernel 2: means + distance(push) term + regularizer --------
__global__ void k_means_dist(float* __restrict__ ws) {
    __shared__ float lmean[C_CLS * E_DIM];
    __shared__ float red[256];
    const int n = blockIdx.x, tid = threadIdx.x;

    const float* gsum = ws + SUMS_OFF + n * C_CLS * E_DIM;
    const float* gcnt = ws + CNT_OFF + n * C_CLS;
    float* gmean = ws + MEAN_OFF + n * C_CLS * E_DIM;

    for (int i = tid; i < C_CLS * E_DIM; i += blockDim.x) {
        const int c = i / E_DIM;
        const float cnt = gcnt[c];
        const float m = (cnt > 0.f) ? gsum[i] / cnt : 0.f;
        lmean[i] = m;
        gmean[i] = m;
    }
    __syncthreads();

    float acc = 0.f;
    for (int idx = tid; idx < CK * CK; idx += blockDim.x) {
        const int i = idx / CK + 1, j = idx % CK + 1;
        if (i != j) {
            float sq = 0.f;
#pragma unroll
            for (int e = 0; e < E_DIM; e++) {
                const float d = lmean[i * E_DIM + e] - lmean[j * E_DIM + e];
                sq += d * d;
            }
            const float dm = sqrtf(sq);
            const float h = fmaxf(3.0f - dm, 0.f);   // 2*DELTA_DIST = 3
            acc += h * h;
        }
    }
    acc *= 1.0f / (float)(CK * (CK - 1));            // BETA = 1

    float racc = 0.f;
    for (int c = tid + 1; c < C_CLS; c += blockDim.x) {
        float sq = 0.f;
#pragma unroll
        for (int e = 0; e < E_DIM; e++) {
            const float m = lmean[c * E_DIM + e];
            sq += m * m;
        }
        racc += sqrtf(sq);
    }
    acc += 0.001f * racc / (float)CK;                // GAMMA = 0.001

    red[tid] = acc;
    __syncthreads();
    for (int s = blockDim.x / 2; s > 0; s >>= 1) {
        if (tid < s) red[tid] += red[tid + s];
        __syncthreads();
    }
    if (tid == 0) atomicAdd(ws + LOSS_OFF, red[0]);
}

// ---------------- Kernel 3: variance (pull) term ----------------
__global__ void k_var(const float* __restrict__ emb, const int* __restrict__ target,
                      float* __restrict__ ws) {
    __shared__ float lmean[C_CLS * LDS_STRIDE];
    __shared__ float lw[C_CLS];
    __shared__ float red[256];
    const int tid = threadIdx.x, n = blockIdx.y;

    const float* gmean = ws + MEAN_OFF + n * C_CLS * E_DIM;
    const float* gcnt = ws + CNT_OFF + n * C_CLS;
    for (int i = tid; i < C_CLS * E_DIM; i += blockDim.x) {
        const int c = i / E_DIM, e = i % E_DIM;
        lmean[c * LDS_STRIDE + e] = gmean[i];
    }
    if (tid < C_CLS) {
        const float cnt = gcnt[tid];
        lw[tid] = (cnt > 0.f) ? 1.0f / (cnt * (float)CK) : 0.f;
    }
    __syncthreads();

    const float4* emb4 = (const float4*)(emb + (size_t)n * E_DIM * P_PIX);
    const int4*   tgt4 = (const int4*)(target + (size_t)n * P_PIX);
    const int stride = gridDim.x * blockDim.x;

    float acc = 0.f;
    for (int g = blockIdx.x * blockDim.x + tid; g < G_PIX; g += stride) {
        const int4 lab = tgt4[g];
        const int bx = lab.x * LDS_STRIDE, by = lab.y * LDS_STRIDE;
        const int bz = lab.z * LDS_STRIDE, bw = lab.w * LDS_STRIDE;
        float sx = 0.f, sy = 0.f, sz = 0.f, sw = 0.f;
#pragma unroll
        for (int e = 0; e < E_DIM; e++) {
            const float4 v = emb4[(size_t)e * G_PIX + g];
            float d;
            d = v.x - lmean[bx + e]; sx += d * d;
            d = v.y - lmean[by + e]; sy += d * d;
            d = v.z - lmean[bz + e]; sz += d * d;
            d = v.w - lmean[bw + e]; sw += d * d;
        }
        float h;
        if (lab.x != 0) { h = fmaxf(sqrtf(sx) - 0.5f, 0.f); acc += h * h * lw[lab.x]; }
        if (lab.y != 0) { h = fmaxf(sqrtf(sy) - 0.5f, 0.f); acc += h * h * lw[lab.y]; }
        if (lab.z != 0) { h = fmaxf(sqrtf(sz) - 0.5f, 0.f); acc += h * h * lw[lab.z]; }
        if (lab.w != 0) { h = fmaxf(sqrtf(sw) - 0.5f, 0.f); acc += h * h * lw[lab.w]; }
    }

    red[tid] = acc;
    __syncthreads();
    for (int s = blockDim.x / 2; s > 0; s >>= 1) {
        if (tid < s) red[tid] += red[tid + s];
        __syncthreads();
    }
    if (tid == 0) atomicAdd(ws + LOSS_OFF, red[0]);
}

// ---------------- Kernel 4: finalize ----------------
__global__ void k_fin(const float* __restrict__ ws, float* __restrict__ out) {
    out[0] = ws[LOSS_OFF] * 0.25f;  // mean over 4 images
}

extern "C" void kernel_launch(void* const* d_in, const int* in_sizes, int n_in,
                              void* d_out, int out_size, void* d_ws, size_t ws_size,
                              hipStream_t stream) {
    const float* emb = (const float*)d_in[0];
    const int* target = (const int*)d_in[1];
    float* out = (float*)d_out;
    float* ws = (float*)d_ws;

    hipMemsetAsync(d_ws, 0, WS_FLOATS * sizeof(float), stream);

    dim3 grid1(160, N_IMG);
    k_sums<<<grid1, 256, 0, stream>>>(emb, target, ws);
    k_means_dist<<<N_IMG, 256, 0, stream>>>(ws);
    k_var<<<grid1, 256, 0, stream>>>(emb, target, ws);
    k_fin<<<1, 1, 0, stream>>>(ws, out);
}

// Round 3
// 190.030 us; speedup vs baseline: 1.3950x; 1.3950x over previous
//
#include <hip/hip_runtime.h>

#define N_IMG 4
#define E_DIM 16
#define P_PIX 320000
#define G_PIX (P_PIX / 4)     // 80000 float4 groups per image-channel
#define C_CLS 20
#define CK 19                 // classes 1..19 (IGNORE = 0 excluded everywhere)
#define LDS_STRIDE 17         // 17 invertible mod 32 -> 20 labels hit 20 distinct banks
#define NREP 4
#define SLICES 20             // k_sums: blocks per (img, channel)

// ws layout (floats): sums[n][c][e], counts[n][c], means[n][c][e], loss
#define SUMS_OFF 0
#define CNT_OFF  (N_IMG * C_CLS * E_DIM)            // 1280
#define MEAN_OFF (CNT_OFF + N_IMG * C_CLS)          // 1360
#define LOSS_OFF (MEAN_OFF + N_IMG * C_CLS * E_DIM) // 2640
#define WS_FLOATS (LOSS_OFF + 1)

// ---------------- Kernel 1: per-class sums + counts (channel-major) ----------------
// block = (slice, channel e, image n); per-thread register accumulators, no hot-loop atomics.
__global__ __launch_bounds__(256, 4) void k_sums(const float* __restrict__ emb,
                                                 const int* __restrict__ target,
                                                 float* __restrict__ ws) {
    const int slice = blockIdx.x;   // 0..SLICES-1
    const int e     = blockIdx.y;   // 0..15
    const int n     = blockIdx.z;   // 0..3
    const int tid   = threadIdx.x;

    const float4* emb4 = (const float4*)emb + (size_t)(n * E_DIM + e) * G_PIX;
    const int4*   tgt4 = (const int4*)target + (size_t)n * G_PIX;

    const int g0 = slice * (G_PIX / SLICES);
    const int g1 = g0 + (G_PIX / SLICES);

    float acc[CK];
#pragma unroll
    for (int c = 0; c < CK; c++) acc[c] = 0.f;

    if (e == 0) {
        float cnt[CK];
#pragma unroll
        for (int c = 0; c < CK; c++) cnt[c] = 0.f;
        for (int g = g0 + tid; g < g1; g += 256) {
            const int4 lb = tgt4[g];
            const float4 v = emb4[g];
#pragma unroll
            for (int c = 1; c < C_CLS; c++) {
                acc[c - 1] += (lb.x == c) ? v.x : 0.f;
                acc[c - 1] += (lb.y == c) ? v.y : 0.f;
                acc[c - 1] += (lb.z == c) ? v.z : 0.f;
                acc[c - 1] += (lb.w == c) ? v.w : 0.f;
                cnt[c - 1] += (lb.x == c) ? 1.f : 0.f;
                cnt[c - 1] += (lb.y == c) ? 1.f : 0.f;
                cnt[c - 1] += (lb.z == c) ? 1.f : 0.f;
                cnt[c - 1] += (lb.w == c) ? 1.f : 0.f;
            }
        }
        // flush counts via LDS
        __shared__ float lcnt[NREP][CK];
        const int rep = tid & (NREP - 1);
        for (int i = tid; i < NREP * CK; i += 256) (&lcnt[0][0])[i] = 0.f;
        __syncthreads();
#pragma unroll
        for (int c = 0; c < CK; c++) atomicAdd(&lcnt[rep][c], cnt[c]);
        __syncthreads();
        if (tid < CK) {
            float v = 0.f;
#pragma unroll
            for (int r = 0; r < NREP; r++) v += lcnt[r][tid];
            atomicAdd(ws + CNT_OFF + n * C_CLS + (tid + 1), v);
        }
    } else {
        for (int g = g0 + tid; g < g1; g += 256) {
            const int4 lb = tgt4[g];
            const float4 v = emb4[g];
#pragma unroll
            for (int c = 1; c < C_CLS; c++) {
                acc[c - 1] += (lb.x == c) ? v.x : 0.f;
                acc[c - 1] += (lb.y == c) ? v.y : 0.f;
                acc[c - 1] += (lb.z == c) ? v.z : 0.f;
                acc[c - 1] += (lb.w == c) ? v.w : 0.f;
            }
        }
    }

    // flush sums via LDS (once per block)
    __shared__ float lsum[NREP][CK];
    const int rep = tid & (NREP - 1);
    for (int i = tid; i < NREP * CK; i += 256) (&lsum[0][0])[i] = 0.f;
    __syncthreads();
#pragma unroll
    for (int c = 0; c < CK; c++) atomicAdd(&lsum[rep][c], acc[c]);
    __syncthreads();
    if (tid < CK) {
        float v = 0.f;
#pragma unroll
        for (int r = 0; r < NREP; r++) v += lsum[r][tid];
        atomicAdd(ws + SUMS_OFF + n * C_CLS * E_DIM + (tid + 1) * E_DIM + e, v);
    }
}

// -------- Kernel 2: means + distance(push) term + regularizer --------
__global__ void k_means_dist(float* __restrict__ ws) {
    __shared__ float lmean[C_CLS * E_DIM];
    __shared__ float red[256];
    const int n = blockIdx.x, tid = threadIdx.x;

    const float* gsum = ws + SUMS_OFF + n * C_CLS * E_DIM;
    const float* gcnt = ws + CNT_OFF + n * C_CLS;
    float* gmean = ws + MEAN_OFF + n * C_CLS * E_DIM;

    for (int i = tid; i < C_CLS * E_DIM; i += blockDim.x) {
        const int c = i / E_DIM;
        const float cnt = gcnt[c];
        const float m = (cnt > 0.f) ? gsum[i] / cnt : 0.f;
        lmean[i] = m;
        gmean[i] = m;
    }
    __syncthreads();

    float acc = 0.f;
    for (int idx = tid; idx < CK * CK; idx += blockDim.x) {
        const int i = idx / CK + 1, j = idx % CK + 1;
        if (i != j) {
            float sq = 0.f;
#pragma unroll
            for (int e = 0; e < E_DIM; e++) {
                const float d = lmean[i * E_DIM + e] - lmean[j * E_DIM + e];
                sq += d * d;
            }
            const float dm = sqrtf(sq);
            const float h = fmaxf(3.0f - dm, 0.f);   // 2*DELTA_DIST = 3
            acc += h * h;
        }
    }
    acc *= 1.0f / (float)(CK * (CK - 1));            // BETA = 1

    float racc = 0.f;
    for (int c = tid + 1; c < C_CLS; c += blockDim.x) {
        float sq = 0.f;
#pragma unroll
        for (int e = 0; e < E_DIM; e++) {
            const float m = lmean[c * E_DIM + e];
            sq += m * m;
        }
        racc += sqrtf(sq);
    }
    acc += 0.001f * racc / (float)CK;                // GAMMA = 0.001

    red[tid] = acc;
    __syncthreads();
    for (int s = blockDim.x / 2; s > 0; s >>= 1) {
        if (tid < s) red[tid] += red[tid + s];
        __syncthreads();
    }
    if (tid == 0) atomicAdd(ws + LOSS_OFF, red[0]);
}

// ---------------- Kernel 3: variance (pull) term ----------------
// one float4-group per thread; all 16 channel loads issued before use (forced MLP)
__global__ __launch_bounds__(256, 4) void k_var(const float* __restrict__ emb,
                                                const int* __restrict__ target,
                                                float* __restrict__ ws) {
    __shared__ float lmean[C_CLS * LDS_STRIDE];
    __shared__ float lw[C_CLS];
    __shared__ float red[256];
    const int tid = threadIdx.x, n = blockIdx.y;

    const float* gmean = ws + MEAN_OFF + n * C_CLS * E_DIM;
    const float* gcnt = ws + CNT_OFF + n * C_CLS;
    for (int i = tid; i < C_CLS * E_DIM; i += blockDim.x) {
        const int c = i / E_DIM, e = i % E_DIM;
        lmean[c * LDS_STRIDE + e] = gmean[i];
    }
    if (tid < C_CLS) {
        const float cnt = gcnt[tid];
        // lw[0] = 0 (cnt[0] never accumulated) -> IGNORE pixels masked branchlessly
        lw[tid] = (cnt > 0.f) ? 1.0f / (cnt * (float)CK) : 0.f;
    }
    __syncthreads();

    float acc = 0.f;
    const int g = blockIdx.x * 256 + tid;
    if (g < G_PIX) {
        const float4* emb4 = (const float4*)emb + (size_t)n * E_DIM * G_PIX;
        const int4 lb = ((const int4*)target)[(size_t)n * G_PIX + g];

        float4 v[E_DIM];
#pragma unroll
        for (int e = 0; e < E_DIM; e++) v[e] = emb4[(size_t)e * G_PIX + g];

        const int bx = lb.x * LDS_STRIDE, by = lb.y * LDS_STRIDE;
        const int bz = lb.z * LDS_STRIDE, bw = lb.w * LDS_STRIDE;
        float sx = 0.f, sy = 0.f, sz = 0.f, sw = 0.f;
#pragma unroll
        for (int e = 0; e < E_DIM; e++) {
            float d;
            d = v[e].x - lmean[bx + e]; sx += d * d;
            d = v[e].y - lmean[by + e]; sy += d * d;
            d = v[e].z - lmean[bz + e]; sz += d * d;
            d = v[e].w - lmean[bw + e]; sw += d * d;
        }
        float h;
        h = fmaxf(sqrtf(sx) - 0.5f, 0.f); acc += h * h * lw[lb.x];
        h = fmaxf(sqrtf(sy) - 0.5f, 0.f); acc += h * h * lw[lb.y];
        h = fmaxf(sqrtf(sz) - 0.5f, 0.f); acc += h * h * lw[lb.z];
        h = fmaxf(sqrtf(sw) - 0.5f, 0.f); acc += h * h * lw[lb.w];
    }

    red[tid] = acc;
    __syncthreads();
    for (int s = 128; s > 0; s >>= 1) {
        if (tid < s) red[tid] += red[tid + s];
        __syncthreads();
    }
    if (tid == 0) atomicAdd(ws + LOSS_OFF, red[0]);
}

// ---------------- Kernel 4: finalize ----------------
__global__ void k_fin(const float* __restrict__ ws, float* __restrict__ out) {
    out[0] = ws[LOSS_OFF] * 0.25f;  // mean over 4 images
}

extern "C" void kernel_launch(void* const* d_in, const int* in_sizes, int n_in,
                              void* d_out, int out_size, void* d_ws, size_t ws_size,
                              hipStream_t stream) {
    const float* emb = (const float*)d_in[0];
    const int* target = (const int*)d_in[1];
    float* out = (float*)d_out;
    float* ws = (float*)d_ws;

    hipMemsetAsync(d_ws, 0, WS_FLOATS * sizeof(float), stream);

    dim3 gs(SLICES, E_DIM, N_IMG);                 // 1280 blocks
    k_sums<<<gs, 256, 0, stream>>>(emb, target, ws);
    k_means_dist<<<N_IMG, 256, 0, stream>>>(ws);
    dim3 gv((G_PIX + 255) / 256, N_IMG);           // 313 x 4 blocks
    k_var<<<gv, 256, 0, stream>>>(emb, target, ws);
    k_fin<<<1, 1, 0, stream>>>(ws, out);
}